// Round 3
// baseline (825.591 us; speedup 1.0000x reference)
//
#include <hip/hip_runtime.h>

#define T_   2048
#define D_   256
#define N_   512
#define BTOT 16

typedef unsigned short ushortT;

// fp32 output layout (out_size = 8,421,377 floats):
//   [0, 8388608)  quantize (B,T,D)
//   [8388608]     diff
//   [8388609, +B*T) embed_ind as float
#define QN   ((size_t)BTOT*T_*D_)
#define IDX0 (QN + 1)

__device__ __forceinline__ float bf2f(ushortT u){
    union { unsigned int i; float f; } c; c.i = ((unsigned int)u) << 16; return c.f;
}
__device__ __forceinline__ void unp8(uint4 p, float* f){
    f[0]=bf2f((ushortT)(p.x & 0xffff)); f[1]=bf2f((ushortT)(p.x >> 16));
    f[2]=bf2f((ushortT)(p.y & 0xffff)); f[3]=bf2f((ushortT)(p.y >> 16));
    f[4]=bf2f((ushortT)(p.z & 0xffff)); f[5]=bf2f((ushortT)(p.z >> 16));
    f[6]=bf2f((ushortT)(p.w & 0xffff)); f[7]=bf2f((ushortT)(p.w >> 16));
}

// ---- dtype probe: bf16 vs fp32 input buffers ------------------------------
__global__ void k_probe(const ushortT* __restrict__ x, int* __restrict__ flg){
    int tid = threadIdx.x;
    ushortT u = x[tid];
    int e = (u >> 7) & 0xff;
    bool ok = (e >= 100 && e <= 140);
    unsigned long long m = __ballot(ok);
    if (tid == 0) *flg = (__popcll(m) >= 55) ? 1 : 0;   // bf16: ~64/64 normals
}

// ---- K1: codebook build for b in [b0, b0+BC) ------------------------------
// 512 blocks (n), 256 threads (d). cbw[bl][n][d] fp32.
template<int BC>
__global__ __launch_bounds__(256) void k_codebook(
    const void* __restrict__ spkin, const void* __restrict__ embin,
    float* __restrict__ cbw, int b0, const int* __restrict__ flagp)
{
    const int isb = *flagp;
    const ushortT* ss = (const ushortT*)spkin;
    const float*   sf = (const float*)spkin;
    const ushortT* es = (const ushortT*)embin;
    const float*   ef = (const float*)embin;

    __shared__ float s2[D_ * 16];     // [k][bl]
    __shared__ float s1[D_ * 16];     // [d][bl]
    __shared__ float red[16 * D_];    // [bl][d]
    __shared__ float nrm[16];

    const int n = blockIdx.x, tid = threadIdx.x;

    for (int e = tid; e < D_ * 16; e += 256){ s2[e] = 0.f; s1[e] = 0.f; }
    __syncthreads();
    for (int e = tid; e < D_ * BC; e += 256){
        int bl = e >> 8, k = e & 255;
        int g2 = (2*BTOT + b0 + bl)*D_ + k;
        int g1 = (1*BTOT + b0 + bl)*D_ + k;
        s2[k*16 + bl] = isb ? bf2f(ss[g2]) : sf[g2];
        s1[k*16 + bl] = isb ? bf2f(ss[g1]) : sf[g1];
    }
    __syncthreads();

    const int d = tid;
    float acc[16];
    #pragma unroll
    for (int b = 0; b < 16; b++) acc[b] = 0.f;

    const size_t rb = ((size_t)n * D_ + d) * D_;

    auto inner = [&](const float* ev, int k0){
        #pragma unroll
        for (int j = 0; j < 8; j++){
            float e = ev[j];
            if (BC == 16){
                const float4* sp = (const float4*)&s2[(k0 + j) * 16];
                float4 q0 = sp[0], q1 = sp[1], q2 = sp[2], q3 = sp[3];
                acc[0]  += e*q0.x; acc[1]  += e*q0.y; acc[2]  += e*q0.z; acc[3]  += e*q0.w;
                acc[4]  += e*q1.x; acc[5]  += e*q1.y; acc[6]  += e*q1.z; acc[7]  += e*q1.w;
                acc[8]  += e*q2.x; acc[9]  += e*q2.y; acc[10] += e*q2.z; acc[11] += e*q2.w;
                acc[12] += e*q3.x; acc[13] += e*q3.y; acc[14] += e*q3.z; acc[15] += e*q3.w;
            } else {
                #pragma unroll
                for (int bl = 0; bl < BC; bl++)
                    acc[bl] += e * s2[(k0 + j)*16 + bl];
            }
        }
    };

    if (isb){
        for (int k0 = 0; k0 < D_; k0 += 8){
            uint4 p = *(const uint4*)(es + rb + k0);
            float ev[8]; unp8(p, ev);
            inner(ev, k0);
        }
    } else {
        for (int k0 = 0; k0 < D_; k0 += 8){
            float4 p0 = *(const float4*)(ef + rb + k0);
            float4 p1 = *(const float4*)(ef + rb + k0 + 4);
            float ev[8] = {p0.x,p0.y,p0.z,p0.w,p1.x,p1.y,p1.z,p1.w};
            inner(ev, k0);
        }
    }

    // norm over d per bl
    #pragma unroll
    for (int bl = 0; bl < BC; bl++) red[bl*D_ + d] = acc[bl]*acc[bl];
    __syncthreads();
    for (int s = 128; s > 0; s >>= 1){
        if (d < s){
            #pragma unroll
            for (int bl = 0; bl < BC; bl++) red[bl*D_ + d] += red[bl*D_ + d + s];
        }
        __syncthreads();
    }
    if (d < BC) nrm[d] = sqrtf(red[d*D_]);
    __syncthreads();

    #pragma unroll
    for (int bl = 0; bl < BC; bl++){
        float cb = acc[bl] / nrm[bl] + s1[d*16 + bl];
        cbw[((size_t)bl*N_ + n)*D_ + d] = cb;
    }
}

// ---- K2: scores GEMM over full N + fused argmin ---------------------------
// grid Bc*16 blocks: (bl, tT); 256 threads; 128 rows x 512 n, K=256.
__global__ __launch_bounds__(256) void k_gemm(
    const void* __restrict__ xin, const float* __restrict__ cbw,
    float* __restrict__ outf, int blk0, const int* __restrict__ flagp)
{
    const int isb = *flagp;
    const int bl = blockIdx.x >> 4, tT = blockIdx.x & 15;
    const int bg = blk0 + bl;

    __shared__ float As[16 * 128];
    __shared__ float Bs[16 * 128];
    __shared__ float e2p[256];        // [n_local][half]
    __shared__ float rv[128 * 17];
    __shared__ int   ri[128 * 17];

    const int tid = threadIdx.x;
    const int tx = tid & 15, ty = tid >> 4;
    const int tl = tid >> 1, half = tid & 1;

    const float*   xf = (const float*)xin;
    const ushortT* xs = (const ushortT*)xin;
    const size_t xbase = ((size_t)bg*T_ + tT*128 + tl)*D_ + half*8;

    float runv[8]; int runi[8];
    #pragma unroll
    for (int i = 0; i < 8; i++){ runv[i] = 3.4e38f; runi[i] = 0x7fffffff; }

    for (int nT = 0; nT < 4; nT++){
        float acc[8][8];
        #pragma unroll
        for (int i = 0; i < 8; i++)
            #pragma unroll
            for (int j = 0; j < 8; j++) acc[i][j] = 0.f;
        float e2part = 0.f;

        const size_t bbase = ((size_t)bl*N_ + nT*128 + tl)*D_ + half*8;

        for (int k0 = 0; k0 < D_; k0 += 16){
            float av[8];
            if (isb){
                uint4 p = *(const uint4*)(xs + xbase + k0);
                unp8(p, av);
            } else {
                float4 p0 = *(const float4*)(xf + xbase + k0);
                float4 p1 = *(const float4*)(xf + xbase + k0 + 4);
                av[0]=p0.x; av[1]=p0.y; av[2]=p0.z; av[3]=p0.w;
                av[4]=p1.x; av[5]=p1.y; av[6]=p1.z; av[7]=p1.w;
            }
            float4 q0 = *(const float4*)(cbw + bbase + k0);
            float4 q1 = *(const float4*)(cbw + bbase + k0 + 4);
            float bv[8] = {q0.x,q0.y,q0.z,q0.w,q1.x,q1.y,q1.z,q1.w};
            #pragma unroll
            for (int j = 0; j < 8; j++) e2part += bv[j]*bv[j];

            #pragma unroll
            for (int j = 0; j < 8; j++) As[(half*8 + j)*128 + tl] = av[j];
            #pragma unroll
            for (int j = 0; j < 8; j++) Bs[(half*8 + j)*128 + tl] = bv[j];
            __syncthreads();

            #pragma unroll
            for (int kl = 0; kl < 16; kl++){
                float4 a0 = *(const float4*)&As[kl*128 + (ty<<2)];
                float4 a1 = *(const float4*)&As[kl*128 + 64 + (ty<<2)];
                float4 c0 = *(const float4*)&Bs[kl*128 + (tx<<2)];
                float4 c1 = *(const float4*)&Bs[kl*128 + 64 + (tx<<2)];
                float ar[8] = {a0.x,a0.y,a0.z,a0.w,a1.x,a1.y,a1.z,a1.w};
                float br[8] = {c0.x,c0.y,c0.z,c0.w,c1.x,c1.y,c1.z,c1.w};
                #pragma unroll
                for (int i = 0; i < 8; i++)
                    #pragma unroll
                    for (int j = 0; j < 8; j++)
                        acc[i][j] += ar[i]*br[j];
            }
            __syncthreads();
        }

        e2p[tl*2 + half] = e2part;
        __syncthreads();

        #pragma unroll
        for (int i = 0; i < 8; i++){
            #pragma unroll
            for (int j = 0; j < 8; j++){
                int nl = (tx<<2) + (j&3) + ((j>>2)<<6);
                float e2c = e2p[nl*2] + e2p[nl*2 + 1];
                float s = e2c - 2.f*acc[i][j];
                int ng = nT*128 + nl;
                if (s < runv[i] || (s == runv[i] && ng < runi[i])){
                    runv[i] = s; runi[i] = ng;
                }
            }
        }
        __syncthreads();
    }

    #pragma unroll
    for (int i = 0; i < 8; i++){
        int row = (ty<<2) + (i&3) + ((i>>2)<<6);
        rv[row*17 + tx] = runv[i];
        ri[row*17 + tx] = runi[i];
    }
    __syncthreads();

    if (tid < 128){
        int row = tid;
        float bestv = 3.4e38f; int bestn = 0x7fffffff;
        #pragma unroll
        for (int m = 0; m < 16; m++){
            float v = rv[row*17 + m]; int n = ri[row*17 + m];
            if (v < bestv || (v == bestv && n < bestn)){ bestv = v; bestn = n; }
        }
        int tg = tT*128 + row;
        outf[IDX0 + (size_t)bg*T_ + tg] = (float)bestn;   // fp32-exact index
    }
}

// ---- K3: gather + quantize write + diff -----------------------------------
// grid Bc*2048 blocks: (bl, t); 256 threads (d).
__global__ __launch_bounds__(256) void k_gather(
    const void* __restrict__ xin, const float* __restrict__ cbw,
    float* __restrict__ outf, float* __restrict__ dif,
    int blk0, const int* __restrict__ flagp)
{
    const int isb = *flagp;
    const int bl = blockIdx.x >> 11, t = blockIdx.x & 2047;
    const int bg = blk0 + bl;
    const int tid = threadIdx.x;

    const int n = (int)outf[IDX0 + (size_t)bg*T_ + t];   // broadcast read

    const float*   xf = (const float*)xin;
    const ushortT* xs = (const ushortT*)xin;
    const size_t rowbase = ((size_t)bg*T_ + t)*D_;
    float xv = isb ? bf2f(xs[rowbase + tid]) : xf[rowbase + tid];
    float q  = cbw[((size_t)bl*N_ + n)*D_ + tid];
    float qm = q - xv;
    float q1 = xv + qm;
    outf[rowbase + tid] = 0.5f*(q + q1);

    float val = qm*qm;
    #pragma unroll
    for (int o = 32; o > 0; o >>= 1) val += __shfl_down(val, o, 64);
    __shared__ float wsum[4];
    if ((tid & 63) == 0) wsum[tid >> 6] = val;
    __syncthreads();
    if (tid == 0)
        atomicAdd(dif, wsum[0] + wsum[1] + wsum[2] + wsum[3]);
}

// ---- K4: finalize diff -----------------------------------------------------
__global__ void k_fin(const float* __restrict__ dif, float* __restrict__ outf){
    if (threadIdx.x == 0)
        outf[QN] = dif[0] * (1.0f / (float)QN);
}

extern "C" void kernel_launch(void* const* d_in, const int* in_sizes, int n_in,
                              void* d_out, int out_size, void* d_ws, size_t ws_size,
                              hipStream_t stream)
{
    const void* x   = d_in[0];
    const void* spk = d_in[1];
    const void* emb = d_in[2];

    // pick largest per-chunk batch count that fits ws_size
    int Bc = 16;
    while (Bc > 1 && ((size_t)Bc*N_*D_*4 + 64) > ws_size) Bc >>= 1;

    char*  ws  = (char*)d_ws;
    float* cbw = (float*)ws;                           // Bc*512*256 fp32
    size_t tail = (size_t)Bc*N_*D_*4;
    float* dif = (float*)(ws + tail);                  // 4 B
    int*   flg = (int*)  (ws + tail + 4);              // 4 B

    float* outf = (float*)d_out;

    hipMemsetAsync(dif, 0, 4, stream);
    k_probe<<<1, 64, 0, stream>>>((const ushortT*)x, flg);

    for (int b0 = 0; b0 < BTOT; b0 += Bc){
        switch (Bc){
            case 16: k_codebook<16><<<512, 256, 0, stream>>>(spk, emb, cbw, b0, flg); break;
            case 8:  k_codebook<8> <<<512, 256, 0, stream>>>(spk, emb, cbw, b0, flg); break;
            case 4:  k_codebook<4> <<<512, 256, 0, stream>>>(spk, emb, cbw, b0, flg); break;
            case 2:  k_codebook<2> <<<512, 256, 0, stream>>>(spk, emb, cbw, b0, flg); break;
            default: k_codebook<1> <<<512, 256, 0, stream>>>(spk, emb, cbw, b0, flg); break;
        }
        k_gemm  <<<Bc*16,   256, 0, stream>>>(x, cbw, outf, b0, flg);
        k_gather<<<Bc*2048, 256, 0, stream>>>(x, cbw, outf, dif, b0, flg);
    }
    k_fin<<<1, 64, 0, stream>>>(dif, outf);
}

// Round 4
// 384.313 us; speedup vs baseline: 2.1482x; 2.1482x over previous
//
#include <hip/hip_runtime.h>

#define T_   2048
#define D_   256
#define N_   512
#define BTOT 16

typedef unsigned short ushortT;

// fp32 output layout (out_size = 8,421,377 floats):
//   [0, 8388608)  quantize (B,T,D) ; [8388608] diff ; [8388609, +B*T) indices
#define QN   ((size_t)BTOT*T_*D_)
#define IDX0 (QN + 1)

__device__ __forceinline__ float bf2f(ushortT u){
    union { unsigned int i; float f; } c; c.i = ((unsigned int)u) << 16; return c.f;
}
__device__ __forceinline__ void unp8(uint4 p, float* f){
    f[0]=bf2f((ushortT)(p.x & 0xffff)); f[1]=bf2f((ushortT)(p.x >> 16));
    f[2]=bf2f((ushortT)(p.y & 0xffff)); f[3]=bf2f((ushortT)(p.y >> 16));
    f[4]=bf2f((ushortT)(p.z & 0xffff)); f[5]=bf2f((ushortT)(p.z >> 16));
    f[6]=bf2f((ushortT)(p.w & 0xffff)); f[7]=bf2f((ushortT)(p.w >> 16));
}
__device__ __forceinline__ void unp4(uint2 p, float* f){
    f[0]=bf2f((ushortT)(p.x & 0xffff)); f[1]=bf2f((ushortT)(p.x >> 16));
    f[2]=bf2f((ushortT)(p.y & 0xffff)); f[3]=bf2f((ushortT)(p.y >> 16));
}

// ---- dtype probe: bf16 vs fp32 input buffers ------------------------------
__global__ void k_probe(const ushortT* __restrict__ x, int* __restrict__ flg){
    int tid = threadIdx.x;
    ushortT u = x[tid];
    int e = (u >> 7) & 0xff;
    bool ok = (e >= 100 && e <= 140);
    unsigned long long m = __ballot(ok);
    if (tid == 0) *flg = (__popcll(m) >= 55) ? 1 : 0;
}

// ---- K1: codebook build for b in [b0, b0+BC) ------------------------------
template<int BC>
__global__ __launch_bounds__(256) void k_codebook(
    const void* __restrict__ spkin, const void* __restrict__ embin,
    float* __restrict__ cbw, int b0, const int* __restrict__ flagp)
{
    const int isb = *flagp;
    const ushortT* ss = (const ushortT*)spkin;
    const float*   sf = (const float*)spkin;
    const ushortT* es = (const ushortT*)embin;
    const float*   ef = (const float*)embin;

    __shared__ float s2[D_ * 16];
    __shared__ float s1[D_ * 16];
    __shared__ float red[16 * D_];
    __shared__ float nrm[16];

    const int n = blockIdx.x, tid = threadIdx.x;

    for (int e = tid; e < D_ * 16; e += 256){ s2[e] = 0.f; s1[e] = 0.f; }
    __syncthreads();
    for (int e = tid; e < D_ * BC; e += 256){
        int bl = e >> 8, k = e & 255;
        int g2 = (2*BTOT + b0 + bl)*D_ + k;
        int g1 = (1*BTOT + b0 + bl)*D_ + k;
        s2[k*16 + bl] = isb ? bf2f(ss[g2]) : sf[g2];
        s1[k*16 + bl] = isb ? bf2f(ss[g1]) : sf[g1];
    }
    __syncthreads();

    const int d = tid;
    float acc[16];
    #pragma unroll
    for (int b = 0; b < 16; b++) acc[b] = 0.f;

    const size_t rb = ((size_t)n * D_ + d) * D_;

    auto inner = [&](const float* ev, int k0){
        #pragma unroll
        for (int j = 0; j < 8; j++){
            float e = ev[j];
            if (BC == 16){
                const float4* sp = (const float4*)&s2[(k0 + j) * 16];
                float4 q0 = sp[0], q1 = sp[1], q2 = sp[2], q3 = sp[3];
                acc[0]  += e*q0.x; acc[1]  += e*q0.y; acc[2]  += e*q0.z; acc[3]  += e*q0.w;
                acc[4]  += e*q1.x; acc[5]  += e*q1.y; acc[6]  += e*q1.z; acc[7]  += e*q1.w;
                acc[8]  += e*q2.x; acc[9]  += e*q2.y; acc[10] += e*q2.z; acc[11] += e*q2.w;
                acc[12] += e*q3.x; acc[13] += e*q3.y; acc[14] += e*q3.z; acc[15] += e*q3.w;
            } else {
                #pragma unroll
                for (int bl = 0; bl < BC; bl++)
                    acc[bl] += e * s2[(k0 + j)*16 + bl];
            }
        }
    };

    if (isb){
        for (int k0 = 0; k0 < D_; k0 += 8){
            uint4 p = *(const uint4*)(es + rb + k0);
            float ev[8]; unp8(p, ev);
            inner(ev, k0);
        }
    } else {
        for (int k0 = 0; k0 < D_; k0 += 8){
            float4 p0 = *(const float4*)(ef + rb + k0);
            float4 p1 = *(const float4*)(ef + rb + k0 + 4);
            float ev[8] = {p0.x,p0.y,p0.z,p0.w,p1.x,p1.y,p1.z,p1.w};
            inner(ev, k0);
        }
    }

    #pragma unroll
    for (int bl = 0; bl < BC; bl++) red[bl*D_ + d] = acc[bl]*acc[bl];
    __syncthreads();
    for (int s = 128; s > 0; s >>= 1){
        if (d < s){
            #pragma unroll
            for (int bl = 0; bl < BC; bl++) red[bl*D_ + d] += red[bl*D_ + d + s];
        }
        __syncthreads();
    }
    if (d < BC) nrm[d] = sqrtf(red[d*D_]);
    __syncthreads();

    #pragma unroll
    for (int bl = 0; bl < BC; bl++){
        float cb = acc[bl] / nrm[bl] + s1[d*16 + bl];
        cbw[((size_t)bl*N_ + n)*D_ + d] = cb;
    }
}

// ---- K2: scores GEMM over full N + fused argmin ---------------------------
// grid Bc*16 blocks: (bl, tT); 512 threads; 128 rows x 512 n (2 x 256), K=256.
__global__ __launch_bounds__(512, 2) void k_gemm(
    const void* __restrict__ xin, const float* __restrict__ cbw,
    float* __restrict__ outf, int blk0, const int* __restrict__ flagp)
{
    const int isb = *flagp;
    const int bl = blockIdx.x >> 4, tT = blockIdx.x & 15;
    const int bg = blk0 + bl;

    __shared__ float As[16 * 132];    // [k][row], stride 132 kills write conflicts
    __shared__ float Bs[16 * 256];    // [k][nrow]
    __shared__ float e2p[512];        // [nrow][half]

    const int tid = threadIdx.x;
    const int tx = tid & 31, ty = tid >> 5;      // ty 0..15
    const int rA = tid >> 2, qA = tid & 3;       // A staging: row 0..127, quarter
    const int rB = tid >> 1, hB = tid & 1;       // B staging: nrow 0..255, half

    const float*   xf = (const float*)xin;
    const ushortT* xs = (const ushortT*)xin;
    const size_t xbase = ((size_t)bg*T_ + tT*128 + rA)*D_ + qA*4;

    float runv[8]; int runi[8];
    #pragma unroll
    for (int i = 0; i < 8; i++){ runv[i] = 3.4e38f; runi[i] = 0x7fffffff; }

    for (int nT = 0; nT < 2; nT++){
        float acc[8][8];
        #pragma unroll
        for (int i = 0; i < 8; i++)
            #pragma unroll
            for (int j = 0; j < 8; j++) acc[i][j] = 0.f;
        float e2acc = 0.f;

        const size_t bbase = ((size_t)bl*N_ + nT*256 + rB)*D_ + hB*8;

        for (int k0 = 0; k0 < D_; k0 += 16){
            float av[4];
            if (isb){
                uint2 p = *(const uint2*)(xs + xbase + k0);
                unp4(p, av);
            } else {
                float4 p = *(const float4*)(xf + xbase + k0);
                av[0]=p.x; av[1]=p.y; av[2]=p.z; av[3]=p.w;
            }
            float bv[8];
            {
                float4 q0 = *(const float4*)(cbw + bbase + k0);
                float4 q1 = *(const float4*)(cbw + bbase + k0 + 4);
                bv[0]=q0.x; bv[1]=q0.y; bv[2]=q0.z; bv[3]=q0.w;
                bv[4]=q1.x; bv[5]=q1.y; bv[6]=q1.z; bv[7]=q1.w;
            }
            #pragma unroll
            for (int j = 0; j < 8; j++) e2acc += bv[j]*bv[j];

            #pragma unroll
            for (int j = 0; j < 4; j++) As[(qA*4 + j)*132 + rA] = av[j];
            #pragma unroll
            for (int j = 0; j < 8; j++) Bs[(hB*8 + j)*256 + rB] = bv[j];
            __syncthreads();

            #pragma unroll
            for (int kl = 0; kl < 16; kl++){
                float4 a0 = *(const float4*)&As[kl*132 + (ty<<2)];
                float4 a1 = *(const float4*)&As[kl*132 + 64 + (ty<<2)];
                float4 c0 = *(const float4*)&Bs[kl*256 + (tx<<2)];
                float4 c1 = *(const float4*)&Bs[kl*256 + 128 + (tx<<2)];
                float ar[8] = {a0.x,a0.y,a0.z,a0.w,a1.x,a1.y,a1.z,a1.w};
                float br[8] = {c0.x,c0.y,c0.z,c0.w,c1.x,c1.y,c1.z,c1.w};
                #pragma unroll
                for (int i = 0; i < 8; i++)
                    #pragma unroll
                    for (int j = 0; j < 8; j++)
                        acc[i][j] += ar[i]*br[j];
            }
            __syncthreads();
        }

        e2p[rB*2 + hB] = e2acc;
        __syncthreads();

        float e2c[8];
        #pragma unroll
        for (int j = 0; j < 8; j++){
            int nl = (tx<<2) + (j&3) + ((j>>2)<<7);
            e2c[j] = e2p[nl*2] + e2p[nl*2 + 1];
        }

        #pragma unroll
        for (int i = 0; i < 8; i++){
            #pragma unroll
            for (int j = 0; j < 8; j++){
                int ng = nT*256 + (tx<<2) + (j&3) + ((j>>2)<<7);
                float s = e2c[j] - 2.f*acc[i][j];
                if (s < runv[i] || (s == runv[i] && ng < runi[i])){
                    runv[i] = s; runi[i] = ng;
                }
            }
        }
        // intervening k0-loop barriers of the next nT protect e2p reuse
    }

    // argmin reduce across the 32 tx lanes (xor masks stay within half-wave)
    #pragma unroll
    for (int m = 16; m >= 1; m >>= 1){
        #pragma unroll
        for (int i = 0; i < 8; i++){
            float ov = __shfl_xor(runv[i], m);
            int   on = __shfl_xor(runi[i], m);
            if (ov < runv[i] || (ov == runv[i] && on < runi[i])){
                runv[i] = ov; runi[i] = on;
            }
        }
    }
    if (tx == 0){
        #pragma unroll
        for (int i = 0; i < 8; i++){
            int row = (ty<<2) + (i&3) + ((i>>2)<<6);
            outf[IDX0 + (size_t)bg*T_ + tT*128 + row] = (float)runi[i];
        }
    }
}

// ---- K3: gather + quantize write + diff partials --------------------------
// grid Bc*2048 blocks: (bl, t); 256 threads (d). Atomics spread over 1024 slots.
__global__ __launch_bounds__(256) void k_gather(
    const void* __restrict__ xin, const float* __restrict__ cbw,
    float* __restrict__ outf, float* __restrict__ part,
    int blk0, const int* __restrict__ flagp)
{
    const int isb = *flagp;
    const int bid = blockIdx.x;
    const int bl = bid >> 11, t = bid & 2047;
    const int bg = blk0 + bl;
    const int tid = threadIdx.x;

    const int n = (int)outf[IDX0 + (size_t)bg*T_ + t];

    const float*   xf = (const float*)xin;
    const ushortT* xs = (const ushortT*)xin;
    const size_t rowbase = ((size_t)bg*T_ + t)*D_;
    float xv = isb ? bf2f(xs[rowbase + tid]) : xf[rowbase + tid];
    float q  = cbw[((size_t)bl*N_ + n)*D_ + tid];
    float qm = q - xv;
    float q1 = xv + qm;
    outf[rowbase + tid] = 0.5f*(q + q1);

    float val = qm*qm;
    #pragma unroll
    for (int o = 32; o > 0; o >>= 1) val += __shfl_down(val, o, 64);
    __shared__ float wsum[4];
    if ((tid & 63) == 0) wsum[tid >> 6] = val;
    __syncthreads();
    if (tid == 0)
        atomicAdd(&part[bid & 1023], wsum[0] + wsum[1] + wsum[2] + wsum[3]);
}

// ---- K4: finalize diff (sum 1024 partials) --------------------------------
__global__ __launch_bounds__(256) void k_fin(const float* __restrict__ part,
                                             float* __restrict__ outf){
    const int tid = threadIdx.x;
    float v = part[tid] + part[tid + 256] + part[tid + 512] + part[tid + 768];
    #pragma unroll
    for (int o = 32; o > 0; o >>= 1) v += __shfl_down(v, o, 64);
    __shared__ float wsum[4];
    if ((tid & 63) == 0) wsum[tid >> 6] = v;
    __syncthreads();
    if (tid == 0)
        outf[QN] = (wsum[0] + wsum[1] + wsum[2] + wsum[3]) * (1.0f / (float)QN);
}

extern "C" void kernel_launch(void* const* d_in, const int* in_sizes, int n_in,
                              void* d_out, int out_size, void* d_ws, size_t ws_size,
                              hipStream_t stream)
{
    const void* x   = d_in[0];
    const void* spk = d_in[1];
    const void* emb = d_in[2];

    // pick largest per-chunk batch count that fits ws_size (cbw + 4KB partials + flag)
    int Bc = 16;
    while (Bc > 1 && ((size_t)Bc*N_*D_*4 + 4096 + 16) > ws_size) Bc >>= 1;

    char*  ws   = (char*)d_ws;
    float* cbw  = (float*)ws;                          // Bc*512*256 fp32
    size_t tail = (size_t)Bc*N_*D_*4;
    float* part = (float*)(ws + tail);                 // 1024 floats
    int*   flg  = (int*)  (ws + tail + 4096);          // 4 B

    float* outf = (float*)d_out;

    hipMemsetAsync(part, 0, 4096, stream);
    k_probe<<<1, 64, 0, stream>>>((const ushortT*)x, flg);

    for (int b0 = 0; b0 < BTOT; b0 += Bc){
        switch (Bc){
            case 16: k_codebook<16><<<512, 256, 0, stream>>>(spk, emb, cbw, b0, flg); break;
            case 8:  k_codebook<8> <<<512, 256, 0, stream>>>(spk, emb, cbw, b0, flg); break;
            case 4:  k_codebook<4> <<<512, 256, 0, stream>>>(spk, emb, cbw, b0, flg); break;
            case 2:  k_codebook<2> <<<512, 256, 0, stream>>>(spk, emb, cbw, b0, flg); break;
            default: k_codebook<1> <<<512, 256, 0, stream>>>(spk, emb, cbw, b0, flg); break;
        }
        k_gemm  <<<Bc*16,   512, 0, stream>>>(x, cbw, outf, b0, flg);
        k_gather<<<Bc*2048, 256, 0, stream>>>(x, cbw, outf, part, b0, flg);
    }
    k_fin<<<1, 256, 0, stream>>>(part, outf);
}